// Round 10
// baseline (265.482 us; speedup 1.0000x reference)
//
#include <hip/hip_runtime.h>
#include <math.h>

// SLAYER MLP forward: spike(psp(W2 @ spike(psp(W1 @ x))))
// B=256, IN=78, HID=16, OUT=20, T=1000, K=100 (SRM alpha, tau=10)
//
// fp64 accumulation everywhere (absmax 0.0 rounds 0-9), fp32 rounding at
// reference materialization points (einsum outputs z1/z2, final u).
//
// Round-10: FULL per-layer fusion (round 9 showed ~34us of the 110us total
// was inter-kernel launch/drain gaps; z1/z2 round-trips are 74MB). Each block
// computes its z-tile INCLUDING the 99-col halo into LDS (mm recompute of the
// halo is cheap: mm VALU floor ~13us), then runs the proven rolled FIR from
// LDS. Building blocks unchanged from their verified versions: round-8 MMROW
// conflict-free lane layout, round-7 rolled period-3 FIR, named scalars only,
// 256-thread single kernels.

#define B_     256
#define IN_    78
#define HID_   16
#define OUT_   20
#define T_     1000
#define TT_    125
#define J_     224              // TT + K - 1
#define ZSTR_  228              // z LDS row stride (floats)
#define XSTR_  260              // activation LDS row stride (224 + zero pad)

// ---------------- FIR building blocks (named scalars only) ----------------
#define GRP(EP, A0,A1,A2,A3, B0,B1,B2,B3, C0,C1,C2) { \
  const double2 e01_ = *(const double2*)(EP); \
  const double2 e23_ = *(const double2*)((EP)+2); \
  u0 += e01_.x*(A3); u1 += e01_.x*(B0); u2 += e01_.x*(B1); u3 += e01_.x*(B2); \
  u4 += e01_.x*(B3); u5 += e01_.x*(C0); u6 += e01_.x*(C1); u7 += e01_.x*(C2); \
  u0 += e01_.y*(A2); u1 += e01_.y*(A3); u2 += e01_.y*(B0); u3 += e01_.y*(B1); \
  u4 += e01_.y*(B2); u5 += e01_.y*(B3); u6 += e01_.y*(C0); u7 += e01_.y*(C1); \
  u0 += e23_.x*(A1); u1 += e23_.x*(A2); u2 += e23_.x*(A3); u3 += e23_.x*(B0); \
  u4 += e23_.x*(B1); u5 += e23_.x*(B2); u6 += e23_.x*(B3); u7 += e23_.x*(C0); \
  u0 += e23_.y*(A0); u1 += e23_.y*(A1); u2 += e23_.y*(A2); u3 += e23_.y*(A3); \
  u4 += e23_.y*(B0); u5 += e23_.y*(B1); u6 += e23_.y*(B2); u7 += e23_.y*(B3); }

#define LOADF(X0,X1,X2,X3, P) { \
  const float4 lf_ = *(const float4*)(P); \
  X0 = (double)lf_.x; X1 = (double)lf_.y; X2 = (double)lf_.z; X3 = (double)lf_.w; }

// Rolled FIR over one zf row (stride ZSTR_), outputs u0..u7 for t = t0+8*q16+d.
// Declares its own window regs; expects zrow, eps_d, u0..u7 in scope.
#define FIR_BODY(ZROW) { \
  double A0,A1,A2,A3,B0,B1,B2,B3,C0,C1,C2,C3; \
  LOADF(A0,A1,A2,A3, (ZROW) + 96); \
  LOADF(B0,B1,B2,B3, (ZROW) + 100); \
  LOADF(C0,C1,C2,C3, (ZROW) + 104); \
  GRP(eps_d, A0,A1,A2,A3, B0,B1,B2,B3, C0,C1,C2) \
  const float*  zp_ = (ZROW) + 92; \
  const double* ep_ = eps_d + 4; \
  _Pragma("unroll 1") \
  for (int k_ = 0; k_ < 8; ++k_) { \
    LOADF(C0,C1,C2,C3, zp_); \
    GRP(ep_,     C0,C1,C2,C3, A0,A1,A2,A3, B0,B1,B2) \
    LOADF(B0,B1,B2,B3, zp_ - 4); \
    GRP(ep_ + 4, B0,B1,B2,B3, C0,C1,C2,C3, A0,A1,A2) \
    LOADF(A0,A1,A2,A3, zp_ - 8); \
    GRP(ep_ + 8, A0,A1,A2,A3, B0,B1,B2,B3, C0,C1,C2) \
    zp_ -= 12; ep_ += 12; \
  } }

__device__ __forceinline__ void init_eps_d(double* eps_d, int tid) {
  if (tid < 100) {
    float a = (float)tid / 10.0f;           // identical fp32 ops to reference
    float e = a * expf(1.0f - a);
    eps_d[tid] = (double)e;                 // exact widening
  }
}

// ---------------- mm building blocks --------------------------------------
// Per i-row: 4 float2 reads (j-pairs at stride 64) + 16 named-scalar dFMA.
// Same lane p reads as its p-partner (broadcast) -> conflict-free (round 8:
// 14K conflicts measured).
#define MMROW(XR, W0, W1) { \
  const float2 f0_ = *(const float2*)((XR)); \
  const float2 f1_ = *(const float2*)((XR) + 64); \
  const float2 f2_ = *(const float2*)((XR) + 128); \
  const float2 f3_ = *(const float2*)((XR) + 192); \
  const double x0_=(double)f0_.x, x1_=(double)f0_.y; \
  const double x2_=(double)f1_.x, x3_=(double)f1_.y; \
  const double x4_=(double)f2_.x, x5_=(double)f2_.y; \
  const double x6_=(double)f3_.x, x7_=(double)f3_.y; \
  m00 += (W0)*x0_; m01 += (W0)*x1_; m02 += (W0)*x2_; m03 += (W0)*x3_; \
  m04 += (W0)*x4_; m05 += (W0)*x5_; m06 += (W0)*x6_; m07 += (W0)*x7_; \
  m10 += (W1)*x0_; m11 += (W1)*x1_; m12 += (W1)*x2_; m13 += (W1)*x3_; \
  m14 += (W1)*x4_; m15 += (W1)*x5_; m16 += (W1)*x6_; m17 += (W1)*x7_; }

// Store one h-pair's 8 j-columns (fp32 rounding = reference z materialization)
// into zf rows 2p, 2p+1 at cols 2q+64e; e=3 only exists for q<16 (j<224).
#define ZSTORE_PAIR(ZBASE0) { \
  float* z0_ = (ZBASE0); \
  float* z1_ = z0_ + ZSTR_; \
  *(float2*)(z0_)       = make_float2((float)m00, (float)m01); \
  *(float2*)(z0_ + 64)  = make_float2((float)m02, (float)m03); \
  *(float2*)(z0_ + 128) = make_float2((float)m04, (float)m05); \
  *(float2*)(z1_)       = make_float2((float)m10, (float)m11); \
  *(float2*)(z1_ + 64)  = make_float2((float)m12, (float)m13); \
  *(float2*)(z1_ + 128) = make_float2((float)m14, (float)m15); \
  if (q < 16) { \
    *(float2*)(z0_ + 192) = make_float2((float)m06, (float)m07); \
    *(float2*)(z1_ + 192) = make_float2((float)m16, (float)m17); \
  } }

// -------- l1f: s1 = spike(FIR(round32(W1 @ x))), fused per (b, tile) -------
// grid = 256 b * 8 tiles; block 256. mm phase: 8 h-pairs x 32 lanes over
// j = 0..223 (z cols incl. halo); FIR phase: 16 h x 16 q16.
__global__ __launch_bounds__(256) void l1f(
    const float* __restrict__ x, const float* __restrict__ W1,
    float* __restrict__ sout)
{
  __shared__ float  xs[13 * XSTR_];   // 13,520 B
  __shared__ float  zf[HID_ * ZSTR_]; // 14,592 B
  __shared__ double wd[16 * 80];      // 10,240 B
  __shared__ __align__(16) double eps_d[100];   // total ~39.2 KB

  const int tid  = threadIdx.x;
  const int b    = blockIdx.x >> 3;
  const int tile = blockIdx.x & 7;
  const int t0   = tile * TT_;

  init_eps_d(eps_d, tid);
  for (int idx = tid; idx < HID_ * IN_; idx += 256)
    wd[(idx / IN_) * 80 + (idx % IN_)] = (double)W1[idx];
  if (tid < HID_ * 4)                              // zero zf pad cols 224..227
    zf[(tid >> 2) * ZSTR_ + 224 + (tid & 3)] = 0.0f;

  const int p = tid >> 5;
  const int q = tid & 31;

  double m00=0,m01=0,m02=0,m03=0,m04=0,m05=0,m06=0,m07=0;
  double m10=0,m11=0,m12=0,m13=0,m14=0,m15=0,m16=0,m17=0;

  for (int ci = 0; ci < 6; ++ci) {
    __syncthreads();
    for (int idx = tid; idx < 13 * XSTR_; idx += 256) {
      const int r = idx / XSTR_, cc = idx % XSTR_;
      const int t = t0 - 99 + cc;
      xs[idx] = (cc < J_ && t >= 0)
                  ? x[((size_t)b * IN_ + ci * 13 + r) * T_ + t] : 0.0f;
    }
    __syncthreads();
    const int wb0 = (2*p) * 80 + ci * 13;
    const int wb1 = wb0 + 80;
#pragma unroll
    for (int i = 0; i < 13; ++i) {
      const float* xr = &xs[i * XSTR_ + 2 * q];
      MMROW(xr, wd[wb0 + i], wd[wb1 + i])
    }
  }
  ZSTORE_PAIR(&zf[(2*p) * ZSTR_ + 2 * q])
  __syncthreads();

  { // FIR + threshold: 16 h x 16 q16 = 256 tasks exactly
    const int h = tid >> 4, q16 = tid & 15;
    const float* zrow = &zf[h * ZSTR_ + 8 * q16];
    double u0=0,u1=0,u2=0,u3=0,u4=0,u5=0,u6=0,u7=0;
    FIR_BODY(zrow)
    const size_t base = ((size_t)b * HID_ + h) * T_ + t0 + 8 * q16;
    const int tb = 8 * q16;
    const float f0=(float)u0, f1=(float)u1, f2=(float)u2, f3=(float)u3;
    const float f4=(float)u4, f5=(float)u5, f6=(float)u6, f7=(float)u7;
    sout[base + 0] = (f0 >= 1.0f) ? 1.0f : 0.0f;   // tb+3 <= 123 < 125 always
    sout[base + 1] = (f1 >= 1.0f) ? 1.0f : 0.0f;
    sout[base + 2] = (f2 >= 1.0f) ? 1.0f : 0.0f;
    sout[base + 3] = (f3 >= 1.0f) ? 1.0f : 0.0f;
    if (tb + 4 < TT_) sout[base + 4] = (f4 >= 1.0f) ? 1.0f : 0.0f;
    if (tb + 5 < TT_) sout[base + 5] = (f5 >= 1.0f) ? 1.0f : 0.0f;
    if (tb + 6 < TT_) sout[base + 6] = (f6 >= 1.0f) ? 1.0f : 0.0f;
    if (tb + 7 < TT_) sout[base + 7] = (f7 >= 1.0f) ? 1.0f : 0.0f;
  }
}

// -------- l2f: out = spike(FIR(round32(W2 @ s1))), fused per (b, tile) -----
// mm phase: pg-loop covers 10 o-pairs with 8 p-slots; FIR: 320 tasks strided.
__global__ __launch_bounds__(256) void l2f(
    const float* __restrict__ s1, const float* __restrict__ W2,
    float* __restrict__ outp)
{
  __shared__ float  ss[HID_ * XSTR_]; // 16,640 B
  __shared__ float  zf[OUT_ * ZSTR_]; // 18,240 B
  __shared__ double wd[OUT_ * HID_];  //  2,560 B
  __shared__ __align__(16) double eps_d[100];   // total ~38.2 KB

  const int tid  = threadIdx.x;
  const int b    = blockIdx.x >> 3;
  const int tile = blockIdx.x & 7;
  const int t0   = tile * TT_;

  init_eps_d(eps_d, tid);
  for (int idx = tid; idx < OUT_ * HID_; idx += 256)   // 320 > 256: strided
    wd[idx] = (double)W2[idx];
  if (tid < OUT_ * 4)                              // zero zf pad cols 224..227
    zf[(tid >> 2) * ZSTR_ + 224 + (tid & 3)] = 0.0f;
  for (int idx = tid; idx < HID_ * XSTR_; idx += 256) {
    const int r = idx / XSTR_, cc = idx % XSTR_;
    const int t = t0 - 99 + cc;
    ss[idx] = (cc < J_ && t >= 0)
                ? s1[((size_t)b * HID_ + r) * T_ + t] : 0.0f;
  }
  __syncthreads();

  const int p = tid >> 5;
  const int q = tid & 31;

  for (int pg = p; pg < 10; pg += 8) {   // p in {0,1} handles a second pair
    double m00=0,m01=0,m02=0,m03=0,m04=0,m05=0,m06=0,m07=0;
    double m10=0,m11=0,m12=0,m13=0,m14=0,m15=0,m16=0,m17=0;
    const int wb0 = (2*pg) * HID_;
    const int wb1 = wb0 + HID_;
#pragma unroll
    for (int i = 0; i < HID_; ++i) {
      const float* xr = &ss[i * XSTR_ + 2 * q];
      MMROW(xr, wd[wb0 + i], wd[wb1 + i])
    }
    ZSTORE_PAIR(&zf[(2*pg) * ZSTR_ + 2 * q])
  }
  __syncthreads();

  for (int task = tid; task < OUT_ * 16; task += 256) {
    const int h = task >> 4, q16 = task & 15;
    const float* zrow = &zf[h * ZSTR_ + 8 * q16];
    double u0=0,u1=0,u2=0,u3=0,u4=0,u5=0,u6=0,u7=0;
    FIR_BODY(zrow)
    const size_t base = ((size_t)b * OUT_ + h) * T_ + t0 + 8 * q16;
    const int tb = 8 * q16;
    const float f0=(float)u0, f1=(float)u1, f2=(float)u2, f3=(float)u3;
    const float f4=(float)u4, f5=(float)u5, f6=(float)u6, f7=(float)u7;
    outp[base + 0] = (f0 >= 1.0f) ? 1.0f : 0.0f;
    outp[base + 1] = (f1 >= 1.0f) ? 1.0f : 0.0f;
    outp[base + 2] = (f2 >= 1.0f) ? 1.0f : 0.0f;
    outp[base + 3] = (f3 >= 1.0f) ? 1.0f : 0.0f;
    if (tb + 4 < TT_) outp[base + 4] = (f4 >= 1.0f) ? 1.0f : 0.0f;
    if (tb + 5 < TT_) outp[base + 5] = (f5 >= 1.0f) ? 1.0f : 0.0f;
    if (tb + 6 < TT_) outp[base + 6] = (f6 >= 1.0f) ? 1.0f : 0.0f;
    if (tb + 7 < TT_) outp[base + 7] = (f7 >= 1.0f) ? 1.0f : 0.0f;
  }
}

extern "C" void kernel_launch(void* const* d_in, const int* in_sizes, int n_in,
                              void* d_out, int out_size, void* d_ws, size_t ws_size,
                              hipStream_t stream) {
  const float* x  = (const float*)d_in[0];
  const float* W1 = (const float*)d_in[1];
  const float* W2 = (const float*)d_in[2];
  float* outp = (float*)d_out;
  float* s1   = (float*)d_ws;          // [256,16,1000] f32 = 16.384 MB

  l1f<<<dim3(B_ * 8), dim3(256), 0, stream>>>(x,  W1, s1);
  l2f<<<dim3(B_ * 8), dim3(256), 0, stream>>>(s1, W2, outp);
}

// Round 11
// 167.104 us; speedup vs baseline: 1.5887x; 1.5887x over previous
//
#include <hip/hip_runtime.h>
#include <math.h>

// SLAYER MLP forward: spike(psp(W2 @ spike(psp(W1 @ x))))
// B=256, IN=78, HID=16, OUT=20, T=1000, K=100 (SRM alpha, tau=10)
//
// fp64 accumulation everywhere (absmax 0.0 rounds 0-10), fp32 rounding at
// reference materialization points (einsum outputs z1/z2, final u).
//
// Round-11: fused 2-kernel structure kept, but with ALL proven elements
// restored (round-10 fusion dropped round-9's issue-early staging and paid
// 5x): (1) l1f stages x via 13 named regs, loads for chunk ci+1 issued
// before computing chunk ci (round-9 mm1's exact pattern); (2) weights in
// LDS as fp32 (fp32 x fp32 widened to fp64 is exact) -> LDS 39.4 -> ~34KB;
// (3) l2f one-shot column staging, no div/mod. MMROW lane layout and rolled
// period-3 FIR unchanged from their verified versions.

#define B_     256
#define IN_    78
#define HID_   16
#define OUT_   20
#define T_     1000
#define TT_    125
#define J_     224              // TT + K - 1
#define ZSTR_  228              // z LDS row stride (floats)
#define XSTR_  256              // activation LDS row stride (pow2, pad zeroed)

// ---------------- FIR building blocks (named scalars only) ----------------
#define GRP(EP, A0,A1,A2,A3, B0,B1,B2,B3, C0,C1,C2) { \
  const double2 e01_ = *(const double2*)(EP); \
  const double2 e23_ = *(const double2*)((EP)+2); \
  u0 += e01_.x*(A3); u1 += e01_.x*(B0); u2 += e01_.x*(B1); u3 += e01_.x*(B2); \
  u4 += e01_.x*(B3); u5 += e01_.x*(C0); u6 += e01_.x*(C1); u7 += e01_.x*(C2); \
  u0 += e01_.y*(A2); u1 += e01_.y*(A3); u2 += e01_.y*(B0); u3 += e01_.y*(B1); \
  u4 += e01_.y*(B2); u5 += e01_.y*(B3); u6 += e01_.y*(C0); u7 += e01_.y*(C1); \
  u0 += e23_.x*(A1); u1 += e23_.x*(A2); u2 += e23_.x*(A3); u3 += e23_.x*(B0); \
  u4 += e23_.x*(B1); u5 += e23_.x*(B2); u6 += e23_.x*(B3); u7 += e23_.x*(C0); \
  u0 += e23_.y*(A0); u1 += e23_.y*(A1); u2 += e23_.y*(A2); u3 += e23_.y*(A3); \
  u4 += e23_.y*(B0); u5 += e23_.y*(B1); u6 += e23_.y*(B2); u7 += e23_.y*(B3); }

#define LOADF(X0,X1,X2,X3, P) { \
  const float4 lf_ = *(const float4*)(P); \
  X0 = (double)lf_.x; X1 = (double)lf_.y; X2 = (double)lf_.z; X3 = (double)lf_.w; }

// Rolled FIR over one zf row; expects zrow, eps_d, u0..u7 in scope.
#define FIR_BODY(ZROW) { \
  double A0,A1,A2,A3,B0,B1,B2,B3,C0,C1,C2,C3; \
  LOADF(A0,A1,A2,A3, (ZROW) + 96); \
  LOADF(B0,B1,B2,B3, (ZROW) + 100); \
  LOADF(C0,C1,C2,C3, (ZROW) + 104); \
  GRP(eps_d, A0,A1,A2,A3, B0,B1,B2,B3, C0,C1,C2) \
  const float*  zp_ = (ZROW) + 92; \
  const double* ep_ = eps_d + 4; \
  _Pragma("unroll 1") \
  for (int k_ = 0; k_ < 8; ++k_) { \
    LOADF(C0,C1,C2,C3, zp_); \
    GRP(ep_,     C0,C1,C2,C3, A0,A1,A2,A3, B0,B1,B2) \
    LOADF(B0,B1,B2,B3, zp_ - 4); \
    GRP(ep_ + 4, B0,B1,B2,B3, C0,C1,C2,C3, A0,A1,A2) \
    LOADF(A0,A1,A2,A3, zp_ - 8); \
    GRP(ep_ + 8, A0,A1,A2,A3, B0,B1,B2,B3, C0,C1,C2) \
    zp_ -= 12; ep_ += 12; \
  } }

__device__ __forceinline__ void init_eps_d(double* eps_d, int tid) {
  if (tid < 100) {
    float a = (float)tid / 10.0f;           // identical fp32 ops to reference
    float e = a * expf(1.0f - a);
    eps_d[tid] = (double)e;                 // exact widening
  }
}

// ---------------- mm building blocks --------------------------------------
// Per i-row: 4 float2 reads (j-pairs at stride 64) + 16 named-scalar dFMA.
// 64 consecutive dwords per e-group across 32 lanes = 2 lanes/bank = free.
#define MMROW(XR, W0, W1) { \
  const float2 f0_ = *(const float2*)((XR)); \
  const float2 f1_ = *(const float2*)((XR) + 64); \
  const float2 f2_ = *(const float2*)((XR) + 128); \
  const float2 f3_ = *(const float2*)((XR) + 192); \
  const double x0_=(double)f0_.x, x1_=(double)f0_.y; \
  const double x2_=(double)f1_.x, x3_=(double)f1_.y; \
  const double x4_=(double)f2_.x, x5_=(double)f2_.y; \
  const double x6_=(double)f3_.x, x7_=(double)f3_.y; \
  m00 += (W0)*x0_; m01 += (W0)*x1_; m02 += (W0)*x2_; m03 += (W0)*x3_; \
  m04 += (W0)*x4_; m05 += (W0)*x5_; m06 += (W0)*x6_; m07 += (W0)*x7_; \
  m10 += (W1)*x0_; m11 += (W1)*x1_; m12 += (W1)*x2_; m13 += (W1)*x3_; \
  m14 += (W1)*x4_; m15 += (W1)*x5_; m16 += (W1)*x6_; m17 += (W1)*x7_; }

// Store one h-pair's j-columns (fp32 rounding = reference z materialization).
#define ZSTORE_PAIR(ZBASE0) { \
  float* z0_ = (ZBASE0); \
  float* z1_ = z0_ + ZSTR_; \
  *(float2*)(z0_)       = make_float2((float)m00, (float)m01); \
  *(float2*)(z0_ + 64)  = make_float2((float)m02, (float)m03); \
  *(float2*)(z0_ + 128) = make_float2((float)m04, (float)m05); \
  *(float2*)(z1_)       = make_float2((float)m10, (float)m11); \
  *(float2*)(z1_ + 64)  = make_float2((float)m12, (float)m13); \
  *(float2*)(z1_ + 128) = make_float2((float)m14, (float)m15); \
  if (q < 16) { \
    *(float2*)(z0_ + 192) = make_float2((float)m06, (float)m07); \
    *(float2*)(z1_ + 192) = make_float2((float)m16, (float)m17); \
  } }

// -------- l1f: s1 = spike(FIR(round32(W1 @ x))), fused per (b, tile) -------
// grid = 256 b * 8 tiles; block 256. Staging: thread owns column c = tid of
// the j-window (13 rows in named regs, issue-early / write-late). mm phase:
// 8 h-pairs x 32 lanes; FIR phase: 16 h x 16 q16.
__global__ __launch_bounds__(256) void l1f(
    const float* __restrict__ x, const float* __restrict__ W1,
    float* __restrict__ sout)
{
  __shared__ float xs[13 * XSTR_];    // 13,312 B
  __shared__ float zf[HID_ * ZSTR_];  // 14,592 B
  __shared__ float wf[16 * 80];       //  5,120 B
  __shared__ __align__(16) double eps_d[100];   // total ~33.8 KB

  const int tid  = threadIdx.x;
  const int b    = blockIdx.x >> 3;
  const int tile = blockIdx.x & 7;
  const int t0   = tile * TT_;

  init_eps_d(eps_d, tid);
  for (int idx = tid; idx < HID_ * IN_; idx += 256)
    wf[(idx / IN_) * 80 + (idx % IN_)] = W1[idx];
  if (tid < HID_ * 4)                              // zero zf pad cols 224..227
    zf[(tid >> 2) * ZSTR_ + 224 + (tid & 3)] = 0.0f;

  const int  c   = tid;                // staging column 0..255
  const int  tg  = t0 - 99 + c;        // global t (max 999)
  const bool cok = (c < J_) && (tg >= 0);

  const int p = tid >> 5;
  const int q = tid & 31;

  double m00=0,m01=0,m02=0,m03=0,m04=0,m05=0,m06=0,m07=0;
  double m10=0,m11=0,m12=0,m13=0,m14=0,m15=0,m16=0,m17=0;
  float g0,g1,g2,g3,g4,g5,g6,g7,g8,g9,g10,g11,g12;

#define ISSUE_L1(CI) { \
    const float* xb_ = x + ((size_t)b * IN_ + (CI) * 13) * T_ + tg; \
    g0  = cok ? xb_[0]       : 0.0f;  g1  = cok ? xb_[T_]      : 0.0f; \
    g2  = cok ? xb_[2  * T_] : 0.0f;  g3  = cok ? xb_[3  * T_] : 0.0f; \
    g4  = cok ? xb_[4  * T_] : 0.0f;  g5  = cok ? xb_[5  * T_] : 0.0f; \
    g6  = cok ? xb_[6  * T_] : 0.0f;  g7  = cok ? xb_[7  * T_] : 0.0f; \
    g8  = cok ? xb_[8  * T_] : 0.0f;  g9  = cok ? xb_[9  * T_] : 0.0f; \
    g10 = cok ? xb_[10 * T_] : 0.0f;  g11 = cok ? xb_[11 * T_] : 0.0f; \
    g12 = cok ? xb_[12 * T_] : 0.0f; }

  ISSUE_L1(0)
  for (int ci = 0; ci < 6; ++ci) {
    __syncthreads();                  // all waves done reading previous chunk
    {
      float* dst = &xs[c];
      dst[0]          = g0;   dst[XSTR_]      = g1;
      dst[2  * XSTR_] = g2;   dst[3  * XSTR_] = g3;
      dst[4  * XSTR_] = g4;   dst[5  * XSTR_] = g5;
      dst[6  * XSTR_] = g6;   dst[7  * XSTR_] = g7;
      dst[8  * XSTR_] = g8;   dst[9  * XSTR_] = g9;
      dst[10 * XSTR_] = g10;  dst[11 * XSTR_] = g11;
      dst[12 * XSTR_] = g12;
    }
    __syncthreads();
    if (ci < 5) ISSUE_L1(ci + 1)      // next chunk's loads fly under compute
    const int wb0 = (2*p) * 80 + ci * 13;
    const int wb1 = wb0 + 80;
#pragma unroll
    for (int i = 0; i < 13; ++i) {
      const float* xr = &xs[i * XSTR_ + 2 * q];
      const double w0 = (double)wf[wb0 + i];
      const double w1 = (double)wf[wb1 + i];
      MMROW(xr, w0, w1)
    }
  }
  ZSTORE_PAIR(&zf[(2*p) * ZSTR_ + 2 * q])
  __syncthreads();

  { // FIR + threshold: 16 h x 16 q16 = 256 tasks exactly
    const int h = tid >> 4, q16 = tid & 15;
    const float* zrow = &zf[h * ZSTR_ + 8 * q16];
    double u0=0,u1=0,u2=0,u3=0,u4=0,u5=0,u6=0,u7=0;
    FIR_BODY(zrow)
    const size_t base = ((size_t)b * HID_ + h) * T_ + t0 + 8 * q16;
    const int tb = 8 * q16;
    const float f0=(float)u0, f1=(float)u1, f2=(float)u2, f3=(float)u3;
    const float f4=(float)u4, f5=(float)u5, f6=(float)u6, f7=(float)u7;
    sout[base + 0] = (f0 >= 1.0f) ? 1.0f : 0.0f;   // tb+3 <= 123 < 125 always
    sout[base + 1] = (f1 >= 1.0f) ? 1.0f : 0.0f;
    sout[base + 2] = (f2 >= 1.0f) ? 1.0f : 0.0f;
    sout[base + 3] = (f3 >= 1.0f) ? 1.0f : 0.0f;
    if (tb + 4 < TT_) sout[base + 4] = (f4 >= 1.0f) ? 1.0f : 0.0f;
    if (tb + 5 < TT_) sout[base + 5] = (f5 >= 1.0f) ? 1.0f : 0.0f;
    if (tb + 6 < TT_) sout[base + 6] = (f6 >= 1.0f) ? 1.0f : 0.0f;
    if (tb + 7 < TT_) sout[base + 7] = (f7 >= 1.0f) ? 1.0f : 0.0f;
  }
}

// -------- l2f: out = spike(FIR(round32(W2 @ s1))), fused per (b, tile) -----
// One-shot column staging (16 rows, no div/mod); mm pg-loop covers 10
// o-pairs with 8 p-slots; FIR: 320 tasks strided.
__global__ __launch_bounds__(256) void l2f(
    const float* __restrict__ s1, const float* __restrict__ W2,
    float* __restrict__ outp)
{
  __shared__ float ss[HID_ * XSTR_];  // 16,384 B
  __shared__ float zf[OUT_ * ZSTR_];  // 18,240 B
  __shared__ float wf[OUT_ * HID_];   //  1,280 B
  __shared__ __align__(16) double eps_d[100];   // total ~36.7 KB

  const int tid  = threadIdx.x;
  const int b    = blockIdx.x >> 3;
  const int tile = blockIdx.x & 7;
  const int t0   = tile * TT_;

  init_eps_d(eps_d, tid);
  for (int idx = tid; idx < OUT_ * HID_; idx += 256)   // 320 > 256: strided
    wf[idx] = W2[idx];
  if (tid < OUT_ * 4)                              // zero zf pad cols 224..227
    zf[(tid >> 2) * ZSTR_ + 224 + (tid & 3)] = 0.0f;
  {
    const int  c   = tid;
    const int  tg  = t0 - 99 + c;
    const bool cok = (c < J_) && (tg >= 0);
    const float* sb = s1 + (size_t)b * HID_ * T_ + tg;
    float* dst = &ss[c];
#pragma unroll
    for (int r = 0; r < HID_; ++r)
      dst[r * XSTR_] = cok ? sb[r * T_] : 0.0f;
  }
  __syncthreads();

  const int p = tid >> 5;
  const int q = tid & 31;

  for (int pg = p; pg < 10; pg += 8) {   // p in {0,1} handles a second pair
    double m00=0,m01=0,m02=0,m03=0,m04=0,m05=0,m06=0,m07=0;
    double m10=0,m11=0,m12=0,m13=0,m14=0,m15=0,m16=0,m17=0;
    const int wb0 = (2*pg) * HID_;
    const int wb1 = wb0 + HID_;
#pragma unroll
    for (int i = 0; i < HID_; ++i) {
      const float* xr = &ss[i * XSTR_ + 2 * q];
      const double w0 = (double)wf[wb0 + i];
      const double w1 = (double)wf[wb1 + i];
      MMROW(xr, w0, w1)
    }
    ZSTORE_PAIR(&zf[(2*pg) * ZSTR_ + 2 * q])
  }
  __syncthreads();

  for (int task = tid; task < OUT_ * 16; task += 256) {
    const int h = task >> 4, q16 = task & 15;
    const float* zrow = &zf[h * ZSTR_ + 8 * q16];
    double u0=0,u1=0,u2=0,u3=0,u4=0,u5=0,u6=0,u7=0;
    FIR_BODY(zrow)
    const size_t base = ((size_t)b * OUT_ + h) * T_ + t0 + 8 * q16;
    const int tb = 8 * q16;
    const float f0=(float)u0, f1=(float)u1, f2=(float)u2, f3=(float)u3;
    const float f4=(float)u4, f5=(float)u5, f6=(float)u6, f7=(float)u7;
    outp[base + 0] = (f0 >= 1.0f) ? 1.0f : 0.0f;
    outp[base + 1] = (f1 >= 1.0f) ? 1.0f : 0.0f;
    outp[base + 2] = (f2 >= 1.0f) ? 1.0f : 0.0f;
    outp[base + 3] = (f3 >= 1.0f) ? 1.0f : 0.0f;
    if (tb + 4 < TT_) outp[base + 4] = (f4 >= 1.0f) ? 1.0f : 0.0f;
    if (tb + 5 < TT_) outp[base + 5] = (f5 >= 1.0f) ? 1.0f : 0.0f;
    if (tb + 6 < TT_) outp[base + 6] = (f6 >= 1.0f) ? 1.0f : 0.0f;
    if (tb + 7 < TT_) outp[base + 7] = (f7 >= 1.0f) ? 1.0f : 0.0f;
  }
}

extern "C" void kernel_launch(void* const* d_in, const int* in_sizes, int n_in,
                              void* d_out, int out_size, void* d_ws, size_t ws_size,
                              hipStream_t stream) {
  const float* x  = (const float*)d_in[0];
  const float* W1 = (const float*)d_in[1];
  const float* W2 = (const float*)d_in[2];
  float* outp = (float*)d_out;
  float* s1   = (float*)d_ws;          // [256,16,1000] f32 = 16.384 MB

  l1f<<<dim3(B_ * 8), dim3(256), 0, stream>>>(x,  W1, s1);
  l2f<<<dim3(B_ * 8), dim3(256), 0, stream>>>(s1, W2, outp);
}